// Round 7
// baseline (300.290 us; speedup 1.0000x reference)
//
#include <hip/hip_runtime.h>
#include <stdint.h>

#define L1D 3072
#define NB 16384
#define CAP 4096            // per-bucket storage stride in sorted[]
#define ROWS 16             // rows per fused block
#define CHUNKS 152          // 16-row chunk slots per bucket (mean 128, +9 sigma margin)
#define TITER 24            // K-steps of 128 floats (512 B per row per step)

typedef float  float4v  __attribute__((ext_vector_type(4)));
typedef short  short8   __attribute__((ext_vector_type(8)));

__device__ __forceinline__ unsigned short f2bf(float f) {
  uint32_t u = __builtin_bit_cast(uint32_t, f);
  u += 0x7fffu + ((u >> 16) & 1u);   // RNE; inputs are finite
  return (unsigned short)(u >> 16);
}

__device__ __forceinline__ void gload_lds16(const void* g, void* l) {
  __builtin_amdgcn_global_load_lds((const __attribute__((address_space(1))) unsigned int*)g,
                                   (__attribute__((address_space(3))) unsigned int*)l, 16, 0, 0);
}

// Combined weights PRE-FRAGMENTED in MFMA B-fragment order:
//   frag(bucket, kk, lane) = 16B at ((bucket*96 + kk)*64 + lane)*8 shorts
//   lane l = sub*16 + r holds W[bucket*16 + r][kk*32 + sub*8 .. +8]
__global__ void prep_kernel(const float* __restrict__ l1w, const float* __restrict__ l1b,
                            const float* __restrict__ l1fw, const float* __restrict__ l1fb,
                            unsigned short* __restrict__ cw, float* __restrict__ cb,
                            int* __restrict__ cur) {
  const int n = blockIdx.y;                       // 0..127  (= bucket*16 + j)
  const int k = blockIdx.x * 256 + threadIdx.x;   // 0..3071
  const unsigned short v = f2bf(l1w[n * L1D + k] + l1fw[(n & 15) * L1D + k]);
  const int kk  = k >> 5;
  const int sub = (k >> 3) & 3;
  const int e   = k & 7;
  const int lane = sub * 16 + (n & 15);
  cw[(((n >> 4) * 96 + kk) * 64 + lane) * 8 + e] = v;
  if (blockIdx.x == 0 && n == 0 && threadIdx.x < 128)
    cb[threadIdx.x] = l1b[threadIdx.x] + l1fb[threadIdx.x & 15];
  if (blockIdx.x == 0 && n == 0 && threadIdx.x < 8) cur[threadIdx.x] = 0;
}

// Two-phase bucket sort: LDS histogram, one global atomic per bucket per
// block (512 total), then direct placement. Order within bucket irrelevant.
__global__ void scatter_kernel(const int* __restrict__ lsi, int* __restrict__ cur,
                               int* __restrict__ sorted) {
  __shared__ int hist[8], base[8];
  const int tid = threadIdx.x;
  if (tid < 8) hist[tid] = 0;
  __syncthreads();
  const int i = blockIdx.x * 256 + tid;
  const int b = lsi[i];
  const int slot = atomicAdd(&hist[b], 1);        // LDS-scope atomic
  __syncthreads();
  if (tid < 8) base[tid] = atomicAdd(&cur[tid], hist[tid]);
  __syncthreads();
  sorted[b * CAP + base[b] + slot] = i;
}

struct __align__(16) EpS {
  float ygp[4][ROWS][20];             // per-wave K-quarter partials, padded stride
  float l2wb[960];                    // bucket slice of l2_w  [n*30+k]
  float outwb[32];
  float l2bb[32];
  float biasb[16];
  int   rows[ROWS];
};                                    // 9344 B

union __align__(16) SMem {
  struct {
    float Af[2][ROWS][128];           // 16 KiB: [buf][row][512B step], chunk-XOR swizzled
    unsigned short Bf[2][4][512];     // 8 KiB:  [buf][wave's kstep][lane*8+e]
  } st;                               // 24576 B -> 6 blocks/CU (LDS-bound)
  EpS ep;
};

// R6 structure at 2x the occupancy: 24 KB LDS -> 6 blocks/CU (vs 3), testing
// the per-CU-concurrency theory for the ~2.3 TB/s effective-read wall. Per
// tile (128 K-floats): wave stages 3 gload_lds (2x A covering 2 rows each +
// 1 B frag), counted vmcnt(3); computes ONE MFMA (its k-quarter ks=wid).
// Same XOR-swizzle class, same epilogue as R6 (verified R3-R6).
__global__ __launch_bounds__(256, 4) void fused_kernel(
    const float* __restrict__ x, const unsigned short* __restrict__ cw,
    const float* __restrict__ cb,
    const float* __restrict__ gl2w, const float* __restrict__ gl2b,
    const float* __restrict__ goutw, const float* __restrict__ goutb,
    const int* __restrict__ cur, const int* __restrict__ sorted,
    float* __restrict__ out) {
  __shared__ SMem sm;
  const int tid  = threadIdx.x;
  const int lane = tid & 63;
  const int wid  = tid >> 6;
  const int bucket = blockIdx.x & 7;     // bucket fast-varying -> dense useful prefix
  const int chunk  = blockIdx.x >> 3;
  const int count  = cur[bucket];
  const int start  = chunk * ROWS;
  if (start >= count) return;            // block-uniform: exits before any barrier

  // A staging: wave wid stages rows wid*4..wid*4+3 via 2 gload_lds, each
  // covering 2 rows (lanes 0-31 row a, 32-63 row b; dest 1KB linear).
  // Source 16B-chunk pre-swizzled ((lane&31) ^ (row&7)); read re-applies XOR.
  const char* aP[2];
#pragma unroll
  for (int q = 0; q < 2; ++q) {
    const int ra = wid * 4 + 2 * q + (lane >> 5);        // block row 0..15
    int sr = start + ra;
    sr = (sr < count) ? sr : (count - 1);                // duplicate last row if padded
    const int grow = sorted[bucket * CAP + sr];
    const int cs = (lane & 31) ^ (ra & 7);               // swizzled 16B chunk in 512B step
    aP[q] = (const char*)x + (size_t)grow * (L1D * 4) + (size_t)cs * 16;
  }
  // B staging: wave stages its own k-step frag kk = t*4 + wid (1 KB).
  const char* bP = (const char*)cw + ((size_t)bucket * 96 * 64 + lane) * 16
                 + (size_t)wid * 1024;

  float4v acc = {0.f, 0.f, 0.f, 0.f};

#define STAGE(BUF_, T_)                                                          \
  {                                                                              \
    _Pragma("unroll")                                                            \
    for (int q = 0; q < 2; ++q)                                                  \
      gload_lds16(aP[q] + (size_t)(T_) * 512, &sm.st.Af[BUF_][wid * 4 + 2 * q][0]); \
    gload_lds16(bP + (size_t)(T_) * 4096, &sm.st.Bf[BUF_][wid][0]);              \
  }

#define COMPUTE(BUF_)                                                            \
  {                                                                              \
    const int r_ = lane & 15, s_ = r_ & 7;                                       \
    const int c1 = wid * 8 + (lane >> 4) * 2;           /* 16B chunk idx */      \
    const float4v lo = *(const float4v*)((const char*)&sm.st.Af[BUF_][r_][0]     \
                                         + ((c1 ^ s_) << 4));                    \
    const float4v hi = *(const float4v*)((const char*)&sm.st.Af[BUF_][r_][0]     \
                                         + (((c1 + 1) ^ s_) << 4));              \
    const short8 afr = short8{(short)f2bf(lo.x), (short)f2bf(lo.y),              \
                              (short)f2bf(lo.z), (short)f2bf(lo.w),              \
                              (short)f2bf(hi.x), (short)f2bf(hi.y),              \
                              (short)f2bf(hi.z), (short)f2bf(hi.w)};             \
    const short8 bfr = *(const short8*)&sm.st.Bf[BUF_][wid][lane * 8];           \
    acc = __builtin_amdgcn_mfma_f32_16x16x32_bf16(afr, bfr, acc, 0, 0, 0);       \
  }

  // prologue: tiles 0,1 in flight (6 loads/wave); wait tile 0 only
  STAGE(0, 0)
  STAGE(1, 1)
  asm volatile("s_waitcnt vmcnt(3)" ::: "memory");
  __builtin_amdgcn_s_barrier();

#pragma unroll 1
  for (int t = 0; t < TITER; ++t) {
    COMPUTE(t & 1)
    asm volatile("" ::: "memory");
    __builtin_amdgcn_s_barrier();                 // all waves done reading buf
    if (t + 2 < TITER) {
      STAGE(t & 1, t + 2)
      asm volatile("s_waitcnt vmcnt(3)" ::: "memory");   // tile t+1 landed; t+2 in flight
    } else {
      asm volatile("s_waitcnt vmcnt(0)" ::: "memory");
    }
    __builtin_amdgcn_s_barrier();                 // everyone's tile t+1 landed
  }
#undef STAGE
#undef COMPUTE

  __syncthreads();   // staging LDS dead; epilogue view begins

  // ---- epilogue: bucket-sliced tables + per-wave k-partials ----
  if (tid < ROWS) {
    const int sr = start + tid;
    sm.ep.rows[tid] = (sr < count) ? sorted[bucket * CAP + sr] : -1;
  }
  if (tid < 32) {
    sm.ep.outwb[tid] = goutw[bucket * 32 + tid];
    sm.ep.l2bb[tid]  = gl2b[bucket * 32 + tid];
  }
  if (tid >= 32 && tid < 48) sm.ep.biasb[tid - 32] = cb[bucket * 16 + (tid - 32)];
  for (int i = tid; i < 960; i += 256) sm.ep.l2wb[i] = gl2w[bucket * 960 + i];
#pragma unroll
  for (int rg = 0; rg < 4; ++rg)       // C/D: col=lane&15, row=(lane>>4)*4+rg
    sm.ep.ygp[wid][(lane >> 4) * 4 + rg][lane & 15] = acc[rg];
  __syncthreads();

  // tail network: 8 threads per row, 4 l2-neurons each, shuffle-reduce (width 8)
  if (tid < ROWS * 8) {
    const int r = tid >> 3, q = tid & 7;
    const int grow = sm.ep.rows[r];
    float act[30];
#pragma unroll
    for (int c = 0; c < 15; ++c) {
      const float v = sm.ep.ygp[0][r][c] + sm.ep.ygp[1][r][c] +
                      sm.ep.ygp[2][r][c] + sm.ep.ygp[3][r][c] + sm.ep.biasb[c];
      act[c]      = fminf(v * v * (127.0f / 128.0f), 1.0f);
      act[15 + c] = fminf(fmaxf(v, 0.0f), 1.0f);
    }
    const float y15 = sm.ep.ygp[0][r][15] + sm.ep.ygp[1][r][15] +
                      sm.ep.ygp[2][r][15] + sm.ep.ygp[3][r][15] + sm.ep.biasb[15];
    float o = 0.0f;
#pragma unroll
    for (int nn = 0; nn < 4; ++nn) {
      const int n = q * 4 + nn;
      float s = sm.ep.l2bb[n];
#pragma unroll
      for (int k = 0; k < 30; ++k) s += act[k] * sm.ep.l2wb[n * 30 + k];
      s = fminf(fmaxf(s, 0.0f), 1.0f);
      o += s * sm.ep.outwb[n];
    }
    o += __shfl_down(o, 4, 8);
    o += __shfl_down(o, 2, 8);
    o += __shfl_down(o, 1, 8);
    if (q == 0 && grow >= 0) out[grow] = o + y15 + goutb[bucket];
  }
}

extern "C" void kernel_launch(void* const* d_in, const int* in_sizes, int n_in,
                              void* d_out, int out_size, void* d_ws, size_t ws_size,
                              hipStream_t stream) {
  const float* x    = (const float*)d_in[0];
  const int*   lsi  = (const int*)d_in[1];
  const float* l1w  = (const float*)d_in[2];
  const float* l1b  = (const float*)d_in[3];
  const float* l1fw = (const float*)d_in[4];
  const float* l1fb = (const float*)d_in[5];
  const float* l2w  = (const float*)d_in[6];
  const float* l2b  = (const float*)d_in[7];
  const float* outw = (const float*)d_in[8];
  const float* outb = (const float*)d_in[9];
  float* out = (float*)d_out;

  unsigned short* cw = (unsigned short*)d_ws;                         // 786432 B (fragment order)
  float* cb   = (float*)((char*)d_ws + 786432);                       // 512 B
  int*   cur  = (int*)  ((char*)d_ws + 786944);                       // 32 B
  int*   sorted = (int*)((char*)d_ws + 786976);                       // 8*4096*4 = 131072 B

  prep_kernel<<<dim3(12, 128), 256, 0, stream>>>(l1w, l1b, l1fw, l1fb, cw, cb, cur);
  scatter_kernel<<<NB / 256, 256, 0, stream>>>(lsi, cur, sorted);
  fused_kernel<<<8 * CHUNKS, 256, 0, stream>>>(x, cw, cb, l2w, l2b, outw, outb,
                                               cur, sorted, out);
}